// Round 11
// baseline (239.217 us; speedup 1.0000x reference)
//
#include <hip/hip_runtime.h>

typedef unsigned short u16;
typedef unsigned int u32;
typedef __attribute__((ext_vector_type(8))) short short8;
typedef __attribute__((ext_vector_type(4))) float f32x4;

#define NDST 32000
#define NSRC 50000
#define MAXDEG 16
#define DH 128
#define NCLS 104
#define SBLK 125     // 32000/256 sort blocks
#define NPAIR 500    // 1000 tiles / 2
#define NBLK_GRU 250 // each block: pairs {499-bid, bid}

#define MFMA(a, b, c) __builtin_amdgcn_mfma_f32_16x16x32_bf16(a, b, c, 0, 0, 0)

__device__ __forceinline__ u16 f2bf(float f) {
  union { float f; u32 u; } v; v.f = f;
  return (u16)((v.u + 0x7FFFu + ((v.u >> 16) & 1u)) >> 16);
}
__device__ __forceinline__ u32 cvtpk(float lo, float hi) {
  u32 r;
  asm("v_cvt_pk_bf16_f32 %0, %1, %2" : "=v"(r) : "v"(lo), "v"(hi));
  return r;
}
__device__ __forceinline__ float rcpf(float x) { return __builtin_amdgcn_rcpf(x); }
__device__ __forceinline__ float sigm(float x) { return rcpf(1.f + __expf(-x)); }
__device__ __forceinline__ float tanh1(float x) {
  return 1.f - 2.f * rcpf(1.f + __expf(2.f * x));
}
__device__ __forceinline__ f32x4 splat4(float x) { f32x4 v = {x, x, x, x}; return v; }

// Fused front: embedding mean (fp32 gather), weight bf16 conversion, degree histogram.
__global__ void k_front(const int* __restrict__ token, const float* __restrict__ emb,
                        const float* __restrict__ wih, const float* __restrict__ whh,
                        const float* __restrict__ wc, const int* __restrict__ deg,
                        u16* __restrict__ featb, u16* __restrict__ wihb,
                        u16* __restrict__ whhb, u16* __restrict__ wcb,
                        int* __restrict__ blkhist) {
  __shared__ int h[16];
  const int bid = blockIdx.x, tid = threadIdx.x;
  const bool do_hist = (bid < SBLK);
  if (do_hist) {
    if (tid < 16) h[tid] = 0;
    __syncthreads();
    atomicAdd(&h[deg[bid * 256 + tid] - 1], 1);
  }
  {
    int gid = bid * 256 + tid;
    int n = gid >> 4, c = gid & 15;
    const int* tk = token + n * 4;
    float a[8];
#pragma unroll
    for (int j = 0; j < 8; ++j) a[j] = 0.f;
#pragma unroll
    for (int s = 0; s < 4; ++s) {
      const float* p = emb + (size_t)tk[s] * DH + c * 8;
#pragma unroll
      for (int j = 0; j < 8; ++j) a[j] += p[j];
    }
    uint4 pk;
    pk.x = cvtpk(a[0] * 0.25f, a[1] * 0.25f);
    pk.y = cvtpk(a[2] * 0.25f, a[3] * 0.25f);
    pk.z = cvtpk(a[4] * 0.25f, a[5] * 0.25f);
    pk.w = cvtpk(a[6] * 0.25f, a[7] * 0.25f);
    *reinterpret_cast<uint4*>(featb + (size_t)n * DH + c * 8) = pk;
  }
  if (bid >= SBLK && bid < SBLK + 192) {
    int i = (bid - SBLK) * 256 + tid;  // < 49152
    wihb[i] = f2bf(wih[i]);
    whhb[i] = f2bf(whh[i]);
    if (i < 112 * DH) { int r = i >> 7; wcb[i] = (r < NCLS) ? f2bf(wc[i]) : (u16)0; }
  }
  if (do_hist) {
    __syncthreads();
    if (tid < 16) blkhist[bid * 16 + tid] = h[tid];
  }
}

__global__ void k_scan(const int* __restrict__ blkhist, int* __restrict__ offs,
                       int* __restrict__ base16) {
  __shared__ int tot_s[16];
  int t = threadIdx.x;
  int k = t >> 4, i = t & 15;
  int loc[8];
  int s = 0;
#pragma unroll
  for (int b = 0; b < 8; ++b) {
    int bb = i * 8 + b;
    int v = (bb < SBLK) ? blkhist[bb * 16 + k] : 0;
    loc[b] = s;
    s += v;
  }
  int ps = s;
#pragma unroll
  for (int d = 1; d < 16; d <<= 1) {
    int o = __shfl_up(ps, d, 16);
    if (i >= d) ps += o;
  }
  int excl = ps - s;
#pragma unroll
  for (int b = 0; b < 8; ++b) {
    int bb = i * 8 + b;
    if (bb < SBLK) offs[bb * 16 + k] = excl + loc[b];
  }
  if (i == 15) tot_s[k] = ps;
  __syncthreads();
  if (t == 0) {
    int run = 0;
    for (int q = 0; q < 16; ++q) { base16[q] = run; run += tot_s[q]; }
  }
}

__global__ void k_scatter(const int* __restrict__ deg, const int* __restrict__ offs,
                          const int* __restrict__ base16, int* __restrict__ perm) {
  __shared__ int lc[16];
  int tid = threadIdx.x;
  if (tid < 16) lc[tid] = 0;
  __syncthreads();
  int node = blockIdx.x * 256 + tid;
  int k = deg[node] - 1;
  int p = atomicAdd(&lc[k], 1);
  perm[base16[k] + offs[blockIdx.x * 16 + k] + p] = node;
}

// ---- fused GRU + LN + classifier: fused-region two-tile schedule ----
// 250 blocks x 512 threads. Per step:
//   [STAGE A,B(t+1)->Xs[nxt] | setprio1 MFMA_A MFMA_B setprio0] bar
//   [EPI_A | EPI_B]                                             bar
// Two independent MFMA chains / two independent transcendental chains per
// region = 2x ILP. Xs double-buffered (stage vs read disjoint); Hb single
// buffer per tile (mid-step barrier separates reads from writes).
__global__ __launch_bounds__(512, 2) void k_gru(
    const int* __restrict__ neigh, const int* __restrict__ deg,
    const int* __restrict__ perm, const u16* __restrict__ featb,
    const u16* __restrict__ wihb, const u16* __restrict__ whhb,
    const float* __restrict__ bih, const float* __restrict__ bhh,
    const float* __restrict__ gamma, const float* __restrict__ beta,
    const u16* __restrict__ wcb, const float* __restrict__ bc,
    float* __restrict__ out) {
  __shared__ u16 Hb[2][32][DH];       // [tile][node][col], swizzled (16KB)
  __shared__ u16 Xs[2][2][32][DH];    // [tile][buf][node][col] (32KB); Hf alias
  __shared__ u16 neigh_s[2][MAXDEG][32];  // u16: idx < 50000 (2KB)
  __shared__ int nid_s[2][32];
  __shared__ int deg_s[2][32];
  __shared__ float gam_s[DH], bet_s[DH];

  const int tid = threadIdx.x;
  const int w = tid >> 6;
  const int l = tid & 63;
  const int l16 = l & 15;
  const int lq = l >> 4;
  const int col = w * 16 + l16;
  const int swzA = (l16 & 7) << 3;    // element XOR for rows l16 / 16+l16
  const int grow = w * 4 + (l >> 4);  // staging row this lane covers
  const int gcol = (l & 15) * 8;      // staging col (elems)
  const int gsw = (grow & 7) << 3;    // source swizzle (elems)

  if (tid < DH) { gam_s[tid] = gamma[tid]; bet_s[tid] = beta[tid]; }

  // resident weights: 24 x short8 = 96 regs, pinned
  short8 Wr[4], Wz[4], Wn[4], Ur[4], Uz[4], Un[4];
#pragma unroll
  for (int kc = 0; kc < 4; ++kc) {
    int ko = kc * 32 + lq * 8;
    const u16* pw = wihb + (size_t)col * DH + ko;
    const u16* pu = whhb + (size_t)col * DH + ko;
    Wr[kc] = *(const short8*)pw;
    Wz[kc] = *(const short8*)(pw + DH * DH);
    Wn[kc] = *(const short8*)(pw + 2 * DH * DH);
    Ur[kc] = *(const short8*)pu;
    Uz[kc] = *(const short8*)(pu + DH * DH);
    Un[kc] = *(const short8*)(pu + 2 * DH * DH);
  }
  float bR = bih[col] + bhh[col];
  float bZ = bih[DH + col] + bhh[DH + col];
  float bXN = bih[2 * DH + col];
  float bHN = bhh[2 * DH + col];
  asm volatile("" : "+v"(Wr[0]), "+v"(Wr[1]), "+v"(Wr[2]), "+v"(Wr[3]));
  asm volatile("" : "+v"(Wz[0]), "+v"(Wz[1]), "+v"(Wz[2]), "+v"(Wz[3]));
  asm volatile("" : "+v"(Wn[0]), "+v"(Wn[1]), "+v"(Wn[2]), "+v"(Wn[3]));
  asm volatile("" : "+v"(Ur[0]), "+v"(Ur[1]), "+v"(Ur[2]), "+v"(Ur[3]));
  asm volatile("" : "+v"(Uz[0]), "+v"(Uz[1]), "+v"(Uz[2]), "+v"(Uz[3]));
  asm volatile("" : "+v"(Un[0]), "+v"(Un[1]), "+v"(Un[2]), "+v"(Un[3]));
  asm volatile("" : "+v"(bR), "+v"(bZ), "+v"(bXN), "+v"(bHN));

#define STAGEX(P, T, B)                                                        \
  do {                                                                         \
    int nrow_ = (int)neigh_s[P][T][grow];                                      \
    const u16* g_ = featb + (size_t)nrow_ * DH + (gcol ^ gsw);                 \
    __builtin_amdgcn_global_load_lds(                                          \
        (const __attribute__((address_space(1))) u16*)g_,                      \
        (__attribute__((address_space(3))) u16*)&Xs[P][B][w * 4][0], 16, 0, 0);\
  } while (0)

#define MFMA_TILE(P, CB, aR0, aR1, aZ0, aZ1, aN0, aN1, aH0, aH1)               \
  do {                                                                         \
    aR0 = splat4(bR); aR1 = splat4(bR);                                        \
    aZ0 = splat4(bZ); aZ1 = splat4(bZ);                                        \
    aN0 = splat4(bXN); aN1 = splat4(bXN);                                      \
    aH0 = splat4(bHN); aH1 = splat4(bHN);                                      \
    _Pragma("unroll") for (int kc = 0; kc < 4; ++kc) {                         \
      int ko = kc * 32 + lq * 8;                                               \
      short8 ax0 = *(const short8*)&Xs[P][CB][l16][ko ^ swzA];                 \
      short8 ax1 = *(const short8*)&Xs[P][CB][16 + l16][ko ^ swzA];            \
      short8 ah0 = *(const short8*)&Hb[P][l16][ko ^ swzA];                     \
      short8 ah1 = *(const short8*)&Hb[P][16 + l16][ko ^ swzA];                \
      aR0 = MFMA(ax0, Wr[kc], aR0);                                            \
      aR1 = MFMA(ax1, Wr[kc], aR1);                                            \
      aZ0 = MFMA(ax0, Wz[kc], aZ0);                                            \
      aZ1 = MFMA(ax1, Wz[kc], aZ1);                                            \
      aN0 = MFMA(ax0, Wn[kc], aN0);                                            \
      aN1 = MFMA(ax1, Wn[kc], aN1);                                            \
      aR0 = MFMA(ah0, Ur[kc], aR0);                                            \
      aR1 = MFMA(ah1, Ur[kc], aR1);                                            \
      aZ0 = MFMA(ah0, Uz[kc], aZ0);                                            \
      aZ1 = MFMA(ah1, Uz[kc], aZ1);                                            \
      aH0 = MFMA(ah0, Un[kc], aH0);                                            \
      aH1 = MFMA(ah1, Un[kc], aH1);                                            \
    }                                                                          \
  } while (0)

#define EPI_TILE(P, HREG, DEGM1, T, aR0, aR1, aZ0, aZ1, aN0, aN1, aH0, aH1)    \
  do {                                                                         \
    _Pragma("unroll") for (int m = 0; m < 2; ++m) {                            \
      f32x4 vR = m ? aR1 : aR0, vZ = m ? aZ1 : aZ0;                            \
      f32x4 vN = m ? aN1 : aN0, vH = m ? aH1 : aH0;                            \
      _Pragma("unroll") for (int r = 0; r < 4; ++r) {                          \
        float rr = sigm(vR[r]);                                                \
        float zz = sigm(vZ[r]);                                                \
        float nn = tanh1(vN[r] + rr * vH[r]);                                  \
        float hN = (1.f - zz) * nn + zz * HREG[m][r];                          \
        if ((T) < DEGM1[m][r]) HREG[m][r] = hN;                                \
      }                                                                        \
      u32 p01 = cvtpk(HREG[m][0], HREG[m][1]);                                 \
      u32 p23 = cvtpk(HREG[m][2], HREG[m][3]);                                 \
      int r0_ = m * 16 + lq * 4;                                               \
      Hb[P][r0_ + 0][col ^ (((r0_ + 0) & 7) << 3)] = (u16)p01;                 \
      Hb[P][r0_ + 1][col ^ (((r0_ + 1) & 7) << 3)] = (u16)(p01 >> 16);         \
      Hb[P][r0_ + 2][col ^ (((r0_ + 2) & 7) << 3)] = (u16)p23;                 \
      Hb[P][r0_ + 3][col ^ (((r0_ + 3) & 7) << 3)] = (u16)(p23 >> 16);         \
    }                                                                          \
  } while (0)

  float* Hf = (float*)&Xs[0][0][0][0];  // 16KB fp32 alias, Xs dead post-loop

#pragma unroll 1
  for (int pass = 0; pass < 2; ++pass) {
    const int pairIdx = pass ? (int)blockIdx.x : (NPAIR - 1 - (int)blockIdx.x);

    __syncthreads();  // previous pass's LDS consumers done
    if (tid < 64) nid_s[tid >> 5][tid & 31] = perm[(pairIdx * 2 + (tid >> 5)) * 32 + (tid & 31)];
    __syncthreads();
#pragma unroll
    for (int e = tid; e < 1024; e += 512) {
      int p = e >> 9, r9 = e & 511, node = r9 >> 4, t = r9 & 15;
      neigh_s[p][t][node] = (u16)neigh[(size_t)nid_s[p][node] * MAXDEG + t];
    }
    if (tid < 64) deg_s[tid >> 5][tid & 31] = deg[nid_s[tid >> 5][tid & 31]];
    {
      uint4 z = {0, 0, 0, 0};
      ((uint4*)Hb[0])[tid] = z;           // 8KB
      ((uint4*)Hb[0])[tid + 512] = z;     // 8KB (Hb[1])
    }
    __syncthreads();  // neigh_s ready for staging
    STAGEX(0, 0, 0);
    STAGEX(1, 0, 0);

    const int tmaxA = deg_s[0][31] - 1;  // sorted ascending within tile
    const int tmaxB = deg_s[1][31] - 1;  // >= tmaxA (adjacent sorted tiles)
    int degm1_0[2][4], degm1_1[2][4];
#pragma unroll
    for (int m = 0; m < 2; ++m)
#pragma unroll
      for (int r = 0; r < 4; ++r) {
        degm1_0[m][r] = deg_s[0][m * 16 + lq * 4 + r] - 1;
        degm1_1[m][r] = deg_s[1][m * 16 + lq * 4 + r] - 1;
      }
    float hreg0[2][4] = {{0, 0, 0, 0}, {0, 0, 0, 0}};
    float hreg1[2][4] = {{0, 0, 0, 0}, {0, 0, 0, 0}};

    __syncthreads();  // drains vmcnt -> Xs buf0 landed

    int cur = 0;
#pragma unroll 1
    for (int t = 0; t < tmaxB; ++t) {
      int nxt = cur ^ 1;
      // region 1: stage t+1 (disjoint buffer) + both tiles' MFMA
      if (t + 1 < tmaxA) STAGEX(0, t + 1, nxt);
      if (t + 1 < tmaxB) STAGEX(1, t + 1, nxt);
      f32x4 AR0, AR1, AZ0, AZ1, AN0, AN1, AH0, AH1;
      f32x4 BR0, BR1, BZ0, BZ1, BN0, BN1, BH0, BH1;
      __builtin_amdgcn_s_setprio(1);
      if (t < tmaxA) MFMA_TILE(0, cur, AR0, AR1, AZ0, AZ1, AN0, AN1, AH0, AH1);
      MFMA_TILE(1, cur, BR0, BR1, BZ0, BZ1, BN0, BN1, BH0, BH1);
      __builtin_amdgcn_s_setprio(0);
      __syncthreads();  // all h(t) reads done; EPI may write Hb
      // region 2: both tiles' gate epilogues
      if (t < tmaxA) EPI_TILE(0, hreg0, degm1_0, t, AR0, AR1, AZ0, AZ1, AN0, AN1, AH0, AH1);
      EPI_TILE(1, hreg1, degm1_1, t, BR0, BR1, BZ0, BZ1, BN0, BN1, BH0, BH1);
      __syncthreads();  // h(t+1) visible; Xs[nxt] landed (vmcnt drained)
      cur = nxt;
    }

    // ---- LN + deg==1 override -> Ft (= Hb[P]) ; then classifier ----
#define LNPASS(HREG, P)                                                        \
  do {                                                                         \
    _Pragma("unroll") for (int m = 0; m < 2; ++m)                              \
        _Pragma("unroll") for (int r = 0; r < 4; ++r)                          \
            Hf[(m * 16 + lq * 4 + r) * DH + col] = HREG[m][r];                 \
    __syncthreads();                                                           \
    {                                                                          \
      int node = tid >> 4, sub = tid & 15;                                     \
      float v[8];                                                              \
      float s = 0.f, s2 = 0.f;                                                 \
      _Pragma("unroll") for (int j = 0; j < 8; ++j) {                          \
        v[j] = Hf[node * DH + sub * 8 + j];                                    \
        s += v[j];                                                             \
        s2 += v[j] * v[j];                                                     \
      }                                                                        \
      s += __shfl_xor(s, 1, 64); s2 += __shfl_xor(s2, 1, 64);                  \
      s += __shfl_xor(s, 2, 64); s2 += __shfl_xor(s2, 2, 64);                  \
      s += __shfl_xor(s, 4, 64); s2 += __shfl_xor(s2, 4, 64);                  \
      s += __shfl_xor(s, 8, 64); s2 += __shfl_xor(s2, 8, 64);                  \
      float mu = s * (1.f / 128.f);                                            \
      float var = s2 * (1.f / 128.f) - mu * mu;                                \
      float rstd = rsqrtf(var + 1e-5f);                                        \
      bool isd1 = (deg_s[P][node] == 1);                                       \
      uint4 fv = *(const uint4*)(featb + (size_t)((int)neigh_s[P][0][node]) * DH + sub * 8); \
      float ln_[8];                                                            \
      _Pragma("unroll") for (int j = 0; j < 8; ++j) {                          \
        int d = sub * 8 + j;                                                   \
        ln_[j] = (v[j] - mu) * rstd * gam_s[d] + bet_s[d];                     \
      }                                                                        \
      uint4 pk;                                                                \
      pk.x = isd1 ? fv.x : cvtpk(ln_[0], ln_[1]);                              \
      pk.y = isd1 ? fv.y : cvtpk(ln_[2], ln_[3]);                              \
      pk.z = isd1 ? fv.z : cvtpk(ln_[4], ln_[5]);                              \
      pk.w = isd1 ? fv.w : cvtpk(ln_[6], ln_[7]);                              \
      int e = (sub * 8) ^ ((node & 7) << 3);                                   \
      *(uint4*)&Hb[P][node][e] = pk;                                           \
    }                                                                          \
    __syncthreads();                                                           \
  } while (0)

    LNPASS(hreg0, 0);
    LNPASS(hreg1, 1);

#define CLS(P)                                                                 \
  if (w < 7) {                                                                 \
    f32x4 c0 = splat4(0.f), c1 = splat4(0.f);                                  \
    _Pragma("unroll") for (int kc = 0; kc < 4; ++kc) {                         \
      int ko = kc * 32 + lq * 8;                                               \
      short8 a0 = *(const short8*)&Hb[P][l16][ko ^ swzA];                      \
      short8 a1 = *(const short8*)&Hb[P][16 + l16][ko ^ swzA];                 \
      short8 b = *(const short8*)(wcb + (size_t)col * DH + ko);                \
      c0 = MFMA(a0, b, c0);                                                    \
      c1 = MFMA(a1, b, c1);                                                    \
    }                                                                          \
    if (col < NCLS) {                                                          \
      float bcv = bc[col];                                                     \
      _Pragma("unroll") for (int m = 0; m < 2; ++m)                            \
          _Pragma("unroll") for (int r = 0; r < 4; ++r) {                      \
        float vv = (m ? c1[r] : c0[r]) + bcv;                                  \
        int rowg = nid_s[P][m * 16 + lq * 4 + r];                              \
        out[(size_t)rowg * NCLS + col] = vv;                                   \
      }                                                                        \
    }                                                                          \
  }

    CLS(0);
    CLS(1);
  }
#undef STAGEX
#undef MFMA_TILE
#undef EPI_TILE
#undef LNPASS
#undef CLS
}

extern "C" void kernel_launch(void* const* d_in, const int* in_sizes, int n_in,
                              void* d_out, int out_size, void* d_ws, size_t ws_size,
                              hipStream_t stream) {
  const int* token = (const int*)d_in[0];
  const int* neigh = (const int*)d_in[1];
  const int* deg = (const int*)d_in[2];
  const float* emb = (const float*)d_in[3];
  const float* wih = (const float*)d_in[4];
  const float* whh = (const float*)d_in[5];
  const float* bih = (const float*)d_in[6];
  const float* bhh = (const float*)d_in[7];
  const float* gamma = (const float*)d_in[8];
  const float* beta = (const float*)d_in[9];
  const float* wc = (const float*)d_in[10];
  const float* bc = (const float*)d_in[11];
  float* out = (float*)d_out;

  u16* featb = (u16*)d_ws;  // 12.8 MB
  u16* wihb = featb + (size_t)NSRC * DH;
  u16* whhb = wihb + 384 * DH;
  u16* wcb = whhb + 384 * DH;
  int* perm = (int*)(wcb + 112 * DH);
  int* blkhist = perm + NDST;
  int* offs = blkhist + SBLK * 16;
  int* base16 = offs + SBLK * 16;

  hipLaunchKernelGGL(k_front, dim3(3125), dim3(256), 0, stream, token, emb, wih, whh, wc,
                     deg, featb, wihb, whhb, wcb, blkhist);
  hipLaunchKernelGGL(k_scan, dim3(1), dim3(256), 0, stream, blkhist, offs, base16);
  hipLaunchKernelGGL(k_scatter, dim3(SBLK), dim3(256), 0, stream, deg, offs, base16, perm);
  hipLaunchKernelGGL(k_gru, dim3(NBLK_GRU), dim3(512), 0, stream, neigh, deg, perm, featb,
                     wihb, whhb, bih, bhh, gamma, beta, wcb, bc, out);
}

// Round 12
// 188.659 us; speedup vs baseline: 1.2680x; 1.2680x over previous
//
#include <hip/hip_runtime.h>

typedef unsigned short u16;
typedef unsigned int u32;
typedef __attribute__((ext_vector_type(8))) short short8;
typedef __attribute__((ext_vector_type(4))) float f32x4;

#define NDST 32000
#define NSRC 50000
#define MAXDEG 16
#define DH 128
#define NCLS 104
#define SBLK 125     // 32000/256 sort blocks
#define NPAIR 500    // 1000 tiles / 2
#define NBLK_GRU 250 // each block: pairs {499-bid, bid}

#define MFMA(a, b, c) __builtin_amdgcn_mfma_f32_16x16x32_bf16(a, b, c, 0, 0, 0)

__device__ __forceinline__ u16 f2bf(float f) {
  union { float f; u32 u; } v; v.f = f;
  return (u16)((v.u + 0x7FFFu + ((v.u >> 16) & 1u)) >> 16);
}
__device__ __forceinline__ u32 cvtpk(float lo, float hi) {
  u32 r;
  asm("v_cvt_pk_bf16_f32 %0, %1, %2" : "=v"(r) : "v"(lo), "v"(hi));
  return r;
}
__device__ __forceinline__ float rcpf(float x) { return __builtin_amdgcn_rcpf(x); }
__device__ __forceinline__ float sigm(float x) { return rcpf(1.f + __expf(-x)); }
__device__ __forceinline__ float tanh1(float x) {
  return 1.f - 2.f * rcpf(1.f + __expf(2.f * x));
}
__device__ __forceinline__ f32x4 splat4(float x) { f32x4 v = {x, x, x, x}; return v; }

// Fused front: embedding mean (fp32 gather), weight bf16 conversion, degree histogram.
__global__ void k_front(const int* __restrict__ token, const float* __restrict__ emb,
                        const float* __restrict__ wih, const float* __restrict__ whh,
                        const float* __restrict__ wc, const int* __restrict__ deg,
                        u16* __restrict__ featb, u16* __restrict__ wihb,
                        u16* __restrict__ whhb, u16* __restrict__ wcb,
                        int* __restrict__ blkhist) {
  __shared__ int h[16];
  const int bid = blockIdx.x, tid = threadIdx.x;
  const bool do_hist = (bid < SBLK);
  if (do_hist) {
    if (tid < 16) h[tid] = 0;
    __syncthreads();
    atomicAdd(&h[deg[bid * 256 + tid] - 1], 1);
  }
  {
    int gid = bid * 256 + tid;
    int n = gid >> 4, c = gid & 15;
    const int* tk = token + n * 4;
    float a[8];
#pragma unroll
    for (int j = 0; j < 8; ++j) a[j] = 0.f;
#pragma unroll
    for (int s = 0; s < 4; ++s) {
      const float* p = emb + (size_t)tk[s] * DH + c * 8;
#pragma unroll
      for (int j = 0; j < 8; ++j) a[j] += p[j];
    }
    uint4 pk;
    pk.x = cvtpk(a[0] * 0.25f, a[1] * 0.25f);
    pk.y = cvtpk(a[2] * 0.25f, a[3] * 0.25f);
    pk.z = cvtpk(a[4] * 0.25f, a[5] * 0.25f);
    pk.w = cvtpk(a[6] * 0.25f, a[7] * 0.25f);
    *reinterpret_cast<uint4*>(featb + (size_t)n * DH + c * 8) = pk;
  }
  if (bid >= SBLK && bid < SBLK + 192) {
    int i = (bid - SBLK) * 256 + tid;  // < 49152
    wihb[i] = f2bf(wih[i]);
    whhb[i] = f2bf(whh[i]);
    if (i < 112 * DH) { int r = i >> 7; wcb[i] = (r < NCLS) ? f2bf(wc[i]) : (u16)0; }
  }
  if (do_hist) {
    __syncthreads();
    if (tid < 16) blkhist[bid * 16 + tid] = h[tid];
  }
}

__global__ void k_scan(const int* __restrict__ blkhist, int* __restrict__ offs,
                       int* __restrict__ base16) {
  __shared__ int tot_s[16];
  int t = threadIdx.x;
  int k = t >> 4, i = t & 15;
  int loc[8];
  int s = 0;
#pragma unroll
  for (int b = 0; b < 8; ++b) {
    int bb = i * 8 + b;
    int v = (bb < SBLK) ? blkhist[bb * 16 + k] : 0;
    loc[b] = s;
    s += v;
  }
  int ps = s;
#pragma unroll
  for (int d = 1; d < 16; d <<= 1) {
    int o = __shfl_up(ps, d, 16);
    if (i >= d) ps += o;
  }
  int excl = ps - s;
#pragma unroll
  for (int b = 0; b < 8; ++b) {
    int bb = i * 8 + b;
    if (bb < SBLK) offs[bb * 16 + k] = excl + loc[b];
  }
  if (i == 15) tot_s[k] = ps;
  __syncthreads();
  if (t == 0) {
    int run = 0;
    for (int q = 0; q < 16; ++q) { base16[q] = run; run += tot_s[q]; }
  }
}

__global__ void k_scatter(const int* __restrict__ deg, const int* __restrict__ offs,
                          const int* __restrict__ base16, int* __restrict__ perm) {
  __shared__ int lc[16];
  int tid = threadIdx.x;
  if (tid < 16) lc[tid] = 0;
  __syncthreads();
  int node = blockIdx.x * 256 + tid;
  int k = deg[node] - 1;
  int p = atomicAdd(&lc[k], 1);
  perm[base16[k] + offs[blockIdx.x * 16 + k] + p] = node;
}

// ---- fused GRU + LN + classifier: R9 two-tile schedule + VALU diet ----
// 250 blocks x 512 threads (8 waves, 2/SIMD). Weights pinned (96 regs).
// Per pair-step: [stage Xs_B(t) | PHASE_A] bar [stage Xs_A(t+1) | PHASE_B] bar.
// Accumulators are PHASE-LOCAL (never live across a barrier — R7/R11 lesson).
__global__ __launch_bounds__(512, 2) void k_gru(
    const int* __restrict__ neigh, const int* __restrict__ deg,
    const int* __restrict__ perm, const u16* __restrict__ featb,
    const u16* __restrict__ wihb, const u16* __restrict__ whhb,
    const float* __restrict__ bih, const float* __restrict__ bhh,
    const float* __restrict__ gamma, const float* __restrict__ beta,
    const u16* __restrict__ wcb, const float* __restrict__ bc,
    float* __restrict__ out) {
  __shared__ u16 Hb[2][2][32][DH];  // [tile][buf][node][col], swizzled (32KB)
  __shared__ u16 Xs[2][32][DH];     // staged X (16KB); fp32 Hf alias post-loop
  __shared__ u16 neigh_s[2][MAXDEG][32];  // u16 indices (2KB)
  __shared__ int nid_s[2][32];
  __shared__ int deg_s[2][32];
  __shared__ float gam_s[DH], bet_s[DH];

  const int tid = threadIdx.x;
  const int w = tid >> 6;
  const int l = tid & 63;
  const int l16 = l & 15;
  const int lq = l >> 4;
  const int col = w * 16 + l16;
  const int swzA = (l16 & 7) << 3;    // element XOR for rows l16 / 16+l16
  const int grow = w * 4 + (l >> 4);  // staging row this lane covers
  const int gcol = (l & 15) * 8;      // staging col (elems)
  const int gsw = (grow & 7) << 3;    // source swizzle (elems)

  if (tid < DH) { gam_s[tid] = gamma[tid]; bet_s[tid] = beta[tid]; }

  // resident weights: 24 x short8 = 96 regs, pinned
  short8 Wr[4], Wz[4], Wn[4], Ur[4], Uz[4], Un[4];
#pragma unroll
  for (int kc = 0; kc < 4; ++kc) {
    int ko = kc * 32 + lq * 8;
    const u16* pw = wihb + (size_t)col * DH + ko;
    const u16* pu = whhb + (size_t)col * DH + ko;
    Wr[kc] = *(const short8*)pw;
    Wz[kc] = *(const short8*)(pw + DH * DH);
    Wn[kc] = *(const short8*)(pw + 2 * DH * DH);
    Ur[kc] = *(const short8*)pu;
    Uz[kc] = *(const short8*)(pu + DH * DH);
    Un[kc] = *(const short8*)(pu + 2 * DH * DH);
  }
  float bR = bih[col] + bhh[col];
  float bZ = bih[DH + col] + bhh[DH + col];
  float bXN = bih[2 * DH + col];
  float bHN = bhh[2 * DH + col];
  asm volatile("" : "+v"(Wr[0]), "+v"(Wr[1]), "+v"(Wr[2]), "+v"(Wr[3]));
  asm volatile("" : "+v"(Wz[0]), "+v"(Wz[1]), "+v"(Wz[2]), "+v"(Wz[3]));
  asm volatile("" : "+v"(Wn[0]), "+v"(Wn[1]), "+v"(Wn[2]), "+v"(Wn[3]));
  asm volatile("" : "+v"(Ur[0]), "+v"(Ur[1]), "+v"(Ur[2]), "+v"(Ur[3]));
  asm volatile("" : "+v"(Uz[0]), "+v"(Uz[1]), "+v"(Uz[2]), "+v"(Uz[3]));
  asm volatile("" : "+v"(Un[0]), "+v"(Un[1]), "+v"(Un[2]), "+v"(Un[3]));
  asm volatile("" : "+v"(bR), "+v"(bZ), "+v"(bXN), "+v"(bHN));

#define STAGEX(P, T)                                                           \
  do {                                                                         \
    int nrow_ = (int)neigh_s[P][T][grow];                                      \
    const u16* g_ = featb + (size_t)nrow_ * DH + (gcol ^ gsw);                 \
    __builtin_amdgcn_global_load_lds(                                          \
        (const __attribute__((address_space(1))) u16*)g_,                      \
        (__attribute__((address_space(3))) u16*)&Xs[P][w * 4][0], 16, 0, 0);   \
  } while (0)

// Self-contained phase: MFMA + gate epilogue; accs never cross a barrier.
#define PHASE(P, CUR, HREG, DEGM1, T)                                          \
  do {                                                                         \
    f32x4 aR0 = splat4(bR), aR1 = splat4(bR), aZ0 = splat4(bZ),                \
          aZ1 = splat4(bZ), aN0 = splat4(bXN), aN1 = splat4(bXN),              \
          aH0 = splat4(bHN), aH1 = splat4(bHN);                                \
    _Pragma("unroll") for (int kc = 0; kc < 4; ++kc) {                         \
      int ko = kc * 32 + lq * 8;                                               \
      short8 ax0 = *(const short8*)&Xs[P][l16][ko ^ swzA];                     \
      short8 ax1 = *(const short8*)&Xs[P][16 + l16][ko ^ swzA];                \
      short8 ah0 = *(const short8*)&Hb[P][CUR][l16][ko ^ swzA];                \
      short8 ah1 = *(const short8*)&Hb[P][CUR][16 + l16][ko ^ swzA];           \
      aR0 = MFMA(ax0, Wr[kc], aR0);                                            \
      aR1 = MFMA(ax1, Wr[kc], aR1);                                            \
      aZ0 = MFMA(ax0, Wz[kc], aZ0);                                            \
      aZ1 = MFMA(ax1, Wz[kc], aZ1);                                            \
      aN0 = MFMA(ax0, Wn[kc], aN0);                                            \
      aN1 = MFMA(ax1, Wn[kc], aN1);                                            \
      aR0 = MFMA(ah0, Ur[kc], aR0);                                            \
      aR1 = MFMA(ah1, Ur[kc], aR1);                                            \
      aZ0 = MFMA(ah0, Uz[kc], aZ0);                                            \
      aZ1 = MFMA(ah1, Uz[kc], aZ1);                                            \
      aH0 = MFMA(ah0, Un[kc], aH0);                                            \
      aH1 = MFMA(ah1, Un[kc], aH1);                                            \
    }                                                                          \
    _Pragma("unroll") for (int m = 0; m < 2; ++m) {                            \
      f32x4 vR = m ? aR1 : aR0, vZ = m ? aZ1 : aZ0;                            \
      f32x4 vN = m ? aN1 : aN0, vH = m ? aH1 : aH0;                            \
      _Pragma("unroll") for (int r = 0; r < 4; ++r) {                          \
        float rr = sigm(vR[r]);                                                \
        float zz = sigm(vZ[r]);                                                \
        float nn = tanh1(vN[r] + rr * vH[r]);                                  \
        float hN = (1.f - zz) * nn + zz * HREG[m][r];                          \
        if ((T) < DEGM1[m][r]) HREG[m][r] = hN;                                \
      }                                                                        \
      u32 p01 = cvtpk(HREG[m][0], HREG[m][1]);                                 \
      u32 p23 = cvtpk(HREG[m][2], HREG[m][3]);                                 \
      int r0_ = m * 16 + lq * 4;                                               \
      Hb[P][(CUR) ^ 1][r0_ + 0][col ^ (((r0_ + 0) & 7) << 3)] = (u16)p01;      \
      Hb[P][(CUR) ^ 1][r0_ + 1][col ^ (((r0_ + 1) & 7) << 3)] = (u16)(p01 >> 16); \
      Hb[P][(CUR) ^ 1][r0_ + 2][col ^ (((r0_ + 2) & 7) << 3)] = (u16)p23;      \
      Hb[P][(CUR) ^ 1][r0_ + 3][col ^ (((r0_ + 3) & 7) << 3)] = (u16)(p23 >> 16); \
    }                                                                          \
  } while (0)

  float* Hf = (float*)&Xs[0][0][0];  // 16KB fp32 alias, Xs dead post-loop

#pragma unroll 1
  for (int pass = 0; pass < 2; ++pass) {
    const int pairIdx = pass ? (int)blockIdx.x : (NPAIR - 1 - (int)blockIdx.x);

    __syncthreads();  // previous pass's LDS consumers done
    if (tid < 64) nid_s[tid >> 5][tid & 31] = perm[(pairIdx * 2 + (tid >> 5)) * 32 + (tid & 31)];
    __syncthreads();
#pragma unroll
    for (int e = tid; e < 1024; e += 512) {
      int p = e >> 9, r9 = e & 511, node = r9 >> 4, t = r9 & 15;
      neigh_s[p][t][node] = (u16)neigh[(size_t)nid_s[p][node] * MAXDEG + t];
    }
    if (tid < 64) deg_s[tid >> 5][tid & 31] = deg[nid_s[tid >> 5][tid & 31]];
    {
      uint4 z = {0, 0, 0, 0};
      ((uint4*)Hb[0][0])[tid] = z;  // 8KB = 512 x 16B
      ((uint4*)Hb[1][0])[tid] = z;
    }
    __syncthreads();  // neigh_s ready for staging
    STAGEX(0, 0);
    STAGEX(1, 0);

    const int tmaxA = deg_s[0][31] - 1;  // sorted ascending within tile
    const int tmaxB = deg_s[1][31] - 1;  // >= tmaxA (adjacent sorted tiles)
    int degm1_0[2][4], degm1_1[2][4];
#pragma unroll
    for (int m = 0; m < 2; ++m)
#pragma unroll
      for (int r = 0; r < 4; ++r) {
        degm1_0[m][r] = deg_s[0][m * 16 + lq * 4 + r] - 1;
        degm1_1[m][r] = deg_s[1][m * 16 + lq * 4 + r] - 1;
      }
    float hreg0[2][4] = {{0, 0, 0, 0}, {0, 0, 0, 0}};
    float hreg1[2][4] = {{0, 0, 0, 0}, {0, 0, 0, 0}};

    __syncthreads();  // drains vmcnt -> Xs(0) landed

    int cur = 0;
#pragma unroll 1
    for (int t = 0; t < tmaxB; ++t) {
      // phase A: stage B's step-t X (B(t-1) reads proven done by last barrier)
      if (t >= 1) STAGEX(1, t);
      if (t < tmaxA) PHASE(0, cur, hreg0, degm1_0, t);
      __syncthreads();
      // phase B: stage A's step-(t+1) X (A(t) reads proven done)
      if (t + 1 < tmaxA) STAGEX(0, t + 1);
      PHASE(1, cur, hreg1, degm1_1, t);
      __syncthreads();
      cur ^= 1;
    }

    // ---- LN + deg==1 override -> Hb[P][0]; then classifier ----
#define LNPASS(HREG, P)                                                        \
  do {                                                                         \
    _Pragma("unroll") for (int m = 0; m < 2; ++m)                              \
        _Pragma("unroll") for (int r = 0; r < 4; ++r)                          \
            Hf[(m * 16 + lq * 4 + r) * DH + col] = HREG[m][r];                 \
    __syncthreads();                                                           \
    {                                                                          \
      int node = tid >> 4, sub = tid & 15;                                     \
      float v[8];                                                              \
      float s = 0.f, s2 = 0.f;                                                 \
      _Pragma("unroll") for (int j = 0; j < 8; ++j) {                          \
        v[j] = Hf[node * DH + sub * 8 + j];                                    \
        s += v[j];                                                             \
        s2 += v[j] * v[j];                                                     \
      }                                                                        \
      s += __shfl_xor(s, 1, 64); s2 += __shfl_xor(s2, 1, 64);                  \
      s += __shfl_xor(s, 2, 64); s2 += __shfl_xor(s2, 2, 64);                  \
      s += __shfl_xor(s, 4, 64); s2 += __shfl_xor(s2, 4, 64);                  \
      s += __shfl_xor(s, 8, 64); s2 += __shfl_xor(s2, 8, 64);                  \
      float mu = s * (1.f / 128.f);                                            \
      float var = s2 * (1.f / 128.f) - mu * mu;                                \
      float rstd = rsqrtf(var + 1e-5f);                                        \
      bool isd1 = (deg_s[P][node] == 1);                                       \
      uint4 fv = *(const uint4*)(featb + (size_t)((int)neigh_s[P][0][node]) * DH + sub * 8); \
      float ln_[8];                                                            \
      _Pragma("unroll") for (int j = 0; j < 8; ++j) {                          \
        int d = sub * 8 + j;                                                   \
        ln_[j] = (v[j] - mu) * rstd * gam_s[d] + bet_s[d];                     \
      }                                                                        \
      uint4 pk;                                                                \
      pk.x = isd1 ? fv.x : cvtpk(ln_[0], ln_[1]);                              \
      pk.y = isd1 ? fv.y : cvtpk(ln_[2], ln_[3]);                              \
      pk.z = isd1 ? fv.z : cvtpk(ln_[4], ln_[5]);                              \
      pk.w = isd1 ? fv.w : cvtpk(ln_[6], ln_[7]);                              \
      int e = (sub * 8) ^ ((node & 7) << 3);                                   \
      *(uint4*)&Hb[P][0][node][e] = pk;                                        \
    }                                                                          \
    __syncthreads();                                                           \
  } while (0)

    LNPASS(hreg0, 0);
    LNPASS(hreg1, 1);

#define CLS(P)                                                                 \
  if (w < 7) {                                                                 \
    f32x4 c0 = splat4(0.f), c1 = splat4(0.f);                                  \
    _Pragma("unroll") for (int kc = 0; kc < 4; ++kc) {                         \
      int ko = kc * 32 + lq * 8;                                               \
      short8 a0 = *(const short8*)&Hb[P][0][l16][ko ^ swzA];                   \
      short8 a1 = *(const short8*)&Hb[P][0][16 + l16][ko ^ swzA];              \
      short8 b = *(const short8*)(wcb + (size_t)col * DH + ko);                \
      c0 = MFMA(a0, b, c0);                                                    \
      c1 = MFMA(a1, b, c1);                                                    \
    }                                                                          \
    if (col < NCLS) {                                                          \
      float bcv = bc[col];                                                     \
      _Pragma("unroll") for (int m = 0; m < 2; ++m)                            \
          _Pragma("unroll") for (int r = 0; r < 4; ++r) {                      \
        float vv = (m ? c1[r] : c0[r]) + bcv;                                  \
        int rowg = nid_s[P][m * 16 + lq * 4 + r];                              \
        out[(size_t)rowg * NCLS + col] = vv;                                   \
      }                                                                        \
    }                                                                          \
  }

    CLS(0);
    CLS(1);
  }
#undef STAGEX
#undef PHASE
#undef LNPASS
#undef CLS
}

extern "C" void kernel_launch(void* const* d_in, const int* in_sizes, int n_in,
                              void* d_out, int out_size, void* d_ws, size_t ws_size,
                              hipStream_t stream) {
  const int* token = (const int*)d_in[0];
  const int* neigh = (const int*)d_in[1];
  const int* deg = (const int*)d_in[2];
  const float* emb = (const float*)d_in[3];
  const float* wih = (const float*)d_in[4];
  const float* whh = (const float*)d_in[5];
  const float* bih = (const float*)d_in[6];
  const float* bhh = (const float*)d_in[7];
  const float* gamma = (const float*)d_in[8];
  const float* beta = (const float*)d_in[9];
  const float* wc = (const float*)d_in[10];
  const float* bc = (const float*)d_in[11];
  float* out = (float*)d_out;

  u16* featb = (u16*)d_ws;  // 12.8 MB
  u16* wihb = featb + (size_t)NSRC * DH;
  u16* whhb = wihb + 384 * DH;
  u16* wcb = whhb + 384 * DH;
  int* perm = (int*)(wcb + 112 * DH);
  int* blkhist = perm + NDST;
  int* offs = blkhist + SBLK * 16;
  int* base16 = offs + SBLK * 16;

  hipLaunchKernelGGL(k_front, dim3(3125), dim3(256), 0, stream, token, emb, wih, whh, wc,
                     deg, featb, wihb, whhb, wcb, blkhist);
  hipLaunchKernelGGL(k_scan, dim3(1), dim3(256), 0, stream, blkhist, offs, base16);
  hipLaunchKernelGGL(k_scatter, dim3(SBLK), dim3(256), 0, stream, deg, offs, base16, perm);
  hipLaunchKernelGGL(k_gru, dim3(NBLK_GRU), dim3(512), 0, stream, neigh, deg, perm, featb,
                     wihb, whhb, bih, bhh, gamma, beta, wcb, bc, out);
}